// Round 6
// baseline (7397.460 us; speedup 1.0000x reference)
//
#include <hip/hip_runtime.h>
#include <hip/hip_bf16.h>
#include <math.h>

// B=512, T=16, DIN=7, D=512, L=2, H=8, HD=64, FF=2048
// R6: "rowchain" — 32 blocks x 1024 threads, each block owns 16 batch rows
// and runs the ENTIRE 16-step 2-layer KV-cached decode block-locally.
// Batch rows are fully independent (attention is per-sample), so there is
// ZERO inter-block communication: no grid barriers, no cooperative launch,
// plain kernel launch + __syncthreads only. Per-CU weight streaming
// (6 MB per (t,l)) is the known ceiling of this structure (~1.3 ms).

typedef __attribute__((__ext_vector_type__(8))) short short8;
typedef __attribute__((__ext_vector_type__(4))) float floatx4;

__device__ inline short8 as_short8(uint4 v){ union U{uint4 u; short8 s;} x; x.u=v; return x.s; }

__device__ inline ushort f2bf(float f){
    __hip_bfloat16 h = __float2bfloat16(f);
    ushort u; __builtin_memcpy(&u, &h, 2); return u;
}
__device__ inline float bf2f(ushort u){
    __hip_bfloat16 h; __builtin_memcpy(&h, &u, 2); return __bfloat162float(h);
}

// ---------------------------------------------------------------------------
// Weight swizzle (unchanged, proven): fp32 W[K][N] -> bf16 16B groups of 8
// k-consecutive values. Group linear index = (kb*4 + q)*N + n.
// blockIdx.z: (mi = z>>1) 0:qkv 1:out 2:ff1 3:ff2, l = z&1.
// ---------------------------------------------------------------------------
__global__ __launch_bounds__(256)
void swz_k(const float* __restrict__ qkv_w, const float* __restrict__ out_w,
           const float* __restrict__ ff1_w, const float* __restrict__ ff2_w,
           ushort* __restrict__ wsw)
{
    int id = blockIdx.z; int l = id & 1; int mi = id >> 1;
    int K, N; const float* src; size_t doff;
    if (mi == 0)      { K = 512;  N = 1536; src = qkv_w + (size_t)l*786432;  doff = (size_t)l*786432; }
    else if (mi == 1) { K = 512;  N = 512;  src = out_w + (size_t)l*262144;  doff = 1572864 + (size_t)l*262144; }
    else if (mi == 2) { K = 512;  N = 2048; src = ff1_w + (size_t)l*1048576; doff = 2097152 + (size_t)l*1048576; }
    else              { K = 2048; N = 512;  src = ff2_w + (size_t)l*1048576; doff = 4194304 + (size_t)l*1048576; }
    int n0 = blockIdx.x * 64, k0 = blockIdx.y * 32;
    if (n0 >= N || k0 >= K) return;
    __shared__ float tt[32][64];
    int tid = threadIdx.x;
    int c = tid & 63, r = tid >> 6;
    #pragma unroll
    for (int i = 0; i < 8; ++i)
        tt[r + i*4][c] = src[(size_t)(k0 + r + i*4)*N + n0 + c];
    __syncthreads();
    int q = tid >> 6, n = tid & 63;
    union { ushort s[8]; uint4 v; } pk;
    #pragma unroll
    for (int i = 0; i < 8; ++i) pk.s[i] = f2bf(tt[q*8 + i][n]);
    ((uint4*)(wsw + doff))[(size_t)((k0 >> 5)*4 + q)*N + n0 + n] = pk.v;
}

// ---------------------------------------------------------------------------
// The rowchain kernel. Grid = 32 blocks x 1024 threads (16 waves).
// Block owns batch rows [blk*16, blk*16+16) for the whole decode.
// ---------------------------------------------------------------------------
__global__ __launch_bounds__(1024, 1)
void rowchain_k(const float* __restrict__ x, const ushort* __restrict__ wsw,
                const float* __restrict__ ip_w, const float* __restrict__ ip_b,
                const float* __restrict__ qkv_b, const float* __restrict__ out_b,
                const float* __restrict__ ln1_s, const float* __restrict__ ln1_b,
                const float* __restrict__ ff_b1, const float* __restrict__ ff_b2,
                const float* __restrict__ ln2_s, const float* __restrict__ ln2_b,
                const float* __restrict__ hw, const float* __restrict__ hb,
                float* __restrict__ out,
                float* __restrict__ hres_g, ushort* __restrict__ ffb_g,
                ushort* __restrict__ kc, ushort* __restrict__ vc)
{
    // LDS: grouped A-operand (padded *17 to kill bank conflicts), a 16x512
    // fp32 scratch (q between P1->P2, z between P3->P3b and P5->P5b),
    // per-wave LN partials, LN stats, head reduction buffers.  ~55.6 KB.
    __shared__ uint4 hA[64*17];          // A fragments, grouped bf16 octets
    __shared__ float zq[16*512];         // q / z scratch (fp32)
    __shared__ float pstat[16][16][2];   // [wave][row][sum,sumsq]
    __shared__ float stats[16][2];       // [row][mean, rstd]
    __shared__ float yacc[16][16][3];    // head partials [wave][row][k]
    __shared__ float ybc[16][3];         // broadcast y per row

    const int tid  = threadIdx.x;          // 0..1023
    const int lane = tid & 63, w = tid >> 6;   // wave 0..15
    const int qd   = lane >> 4, li = lane & 15;
    const int blk  = blockIdx.x;           // 0..31
    const int pm   = tid & 15, pg = tid >> 4;  // pack map: row 0..15, octet 0..63

    float*  hres = hres_g + blk*8192;      // [16][512] fp32 residual stream
    ushort* ffb  = ffb_g  + (size_t)blk*32768;  // [16][2048] bf16 ff1 out
    const int CPL = 4194304;               // kv elems per layer

    // ---- t=0 embed: pe(0) -> sin=0 for even d, cos=1 for odd d
    {
        int b = blk*16 + pm;
        #pragma unroll
        for (int j = 0; j < 8; ++j){
            int d = pg*8 + j;
            float pe = (d & 1) ? 1.0f : 0.0f;
            float acc = ip_b[d] + pe;
            #pragma unroll
            for (int i = 0; i < 7; ++i)
                acc += x[(b*16 + 0)*7 + i] * ip_w[i*512 + d];
            hres[pm*512 + d] = acc;
        }
    }
    __syncthreads();

    for (int t = 0; t < 16; ++t){
        for (int l = 0; l < 2; ++l){
            // ======== P1a: pack hres (fp32) -> hA (bf16 octets) ========
            {
                float4 v0 = *(const float4*)&hres[pm*512 + pg*8];
                float4 v1 = *(const float4*)&hres[pm*512 + pg*8 + 4];
                union { ushort s[8]; uint4 u; } pk;
                pk.s[0]=f2bf(v0.x); pk.s[1]=f2bf(v0.y); pk.s[2]=f2bf(v0.z); pk.s[3]=f2bf(v0.w);
                pk.s[4]=f2bf(v1.x); pk.s[5]=f2bf(v1.y); pk.s[6]=f2bf(v1.z); pk.s[7]=f2bf(v1.w);
                hA[pg*17 + pm] = pk.u;
            }
            __syncthreads();

            // ======== P1b: QKV GEMM, M=16 x N=1536, K=512 ========
            // wave w -> 6 n-tiles; q -> zq (fp32 LDS), k/v -> global cache
            {
                const uint4* Bg = (const uint4*)(wsw + (size_t)l*786432);
                const float* qb = qkv_b + l*1536;
                ushort* kcl = kc + (size_t)l*CPL;
                ushort* vcl = vc + (size_t)l*CPL;
                floatx4 acc[6] = {};
                for (int kb = 0; kb < 16; ++kb){
                    short8 af = as_short8(hA[(kb*4 + qd)*17 + li]);
                    #pragma unroll
                    for (int c = 0; c < 6; ++c){
                        int n = (w*6 + c)*16 + li;
                        short8 bf = as_short8(Bg[(size_t)(kb*4 + qd)*1536 + n]);
                        acc[c] = __builtin_amdgcn_mfma_f32_16x16x32_bf16(af, bf, acc[c], 0, 0, 0);
                    }
                }
                #pragma unroll
                for (int c = 0; c < 6; ++c){
                    #pragma unroll
                    for (int r = 0; r < 4; ++r){
                        int m = qd*4 + r;
                        int n = (w*6 + c)*16 + li;
                        float v = acc[c][r] + qb[n];
                        if (n < 512){
                            zq[m*512 + n] = v;
                        } else if (n < 1024){
                            int z = n - 512; int b = blk*16 + m;
                            kcl[(((size_t)b*8 + (z >> 6))*16 + t)*64 + (z & 63)] = f2bf(v);
                        } else {
                            int z = n - 1024; int b = blk*16 + m;
                            vcl[(((size_t)b*8 + (z >> 6))*16 + t)*64 + (z & 63)] = f2bf(v);
                        }
                    }
                }
            }
            __syncthreads();

            // ======== P2: attention (128 pairs, 8 per wave) ========
            // output written bf16 directly into hA grouped layout (A of P3)
            {
                const ushort* kcl = kc + (size_t)l*CPL;
                const ushort* vcl = vc + (size_t)l*CPL;
                #pragma unroll
                for (int p = 0; p < 8; ++p){
                    int pair = w*8 + p;
                    int bl = pair >> 3, hh = pair & 7;
                    float qv = zq[bl*512 + hh*64 + lane];
                    const ushort* kp = kcl + (((size_t)(blk*16 + bl)*8 + hh)*16)*64;
                    const ushort* vp = vcl + (((size_t)(blk*16 + bl)*8 + hh)*16)*64;
                    float m_ = -1e30f, s_ = 0.0f, o_ = 0.0f;
                    for (int j = 0; j <= t; ++j){
                        float pq = qv * bf2f(kp[j*64 + lane]);
                        #pragma unroll
                        for (int off = 32; off; off >>= 1) pq += __shfl_xor(pq, off);
                        pq *= 0.125f;
                        float nm = fmaxf(m_, pq);
                        float sc = expf(m_ - nm);
                        float e  = expf(pq - nm);
                        s_ = s_*sc + e;
                        o_ = o_*sc + e*bf2f(vp[j*64 + lane]);
                        m_ = nm;
                    }
                    int g = hh*8 + (lane >> 3);
                    ((ushort*)hA)[(g*17 + bl)*8 + (lane & 7)] = f2bf(o_ / s_);
                }
            }
            __syncthreads();

            // ======== P3: out-proj + bias + resid -> z (LDS) + LN1 partials
            {
                const uint4* Bg = (const uint4*)(wsw + 1572864 + (size_t)l*262144);
                const float* ob = out_b + l*512;
                floatx4 acc[2] = {};
                for (int kb = 0; kb < 16; ++kb){
                    short8 af = as_short8(hA[(kb*4 + qd)*17 + li]);
                    #pragma unroll
                    for (int c = 0; c < 2; ++c){
                        int n = (w*2 + c)*16 + li;
                        short8 bf = as_short8(Bg[(size_t)(kb*4 + qd)*512 + n]);
                        acc[c] = __builtin_amdgcn_mfma_f32_16x16x32_bf16(af, bf, acc[c], 0, 0, 0);
                    }
                }
                float ps[4] = {}, pq2[4] = {};
                #pragma unroll
                for (int c = 0; c < 2; ++c){
                    #pragma unroll
                    for (int r = 0; r < 4; ++r){
                        int m = qd*4 + r;
                        int n = (w*2 + c)*16 + li;
                        float zv = acc[c][r] + ob[n] + hres[m*512 + n];
                        zq[m*512 + n] = zv;
                        ps[r] += zv; pq2[r] += zv*zv;
                    }
                }
                #pragma unroll
                for (int off = 1; off < 16; off <<= 1){
                    #pragma unroll
                    for (int r = 0; r < 4; ++r){
                        ps[r]  += __shfl_xor(ps[r],  off);
                        pq2[r] += __shfl_xor(pq2[r], off);
                    }
                }
                if (li == 0){
                    #pragma unroll
                    for (int r = 0; r < 4; ++r){
                        pstat[w][qd*4 + r][0] = ps[r];
                        pstat[w][qd*4 + r][1] = pq2[r];
                    }
                }
            }
            __syncthreads();
            if (tid < 16){
                float s = 0.f, sq = 0.f;
                #pragma unroll
                for (int wv = 0; wv < 16; ++wv){ s += pstat[wv][tid][0]; sq += pstat[wv][tid][1]; }
                float mean = s * (1.0f/512.0f);
                float var  = sq * (1.0f/512.0f) - mean*mean;
                stats[tid][0] = mean;
                stats[tid][1] = rsqrtf(var + 1e-5f);
            }
            __syncthreads();

            // ======== P3b: LN1 -> hres (new resid) + hA pack ========
            {
                const float* g1  = ln1_s + l*512;
                const float* be1 = ln1_b + l*512;
                float mean = stats[pm][0], rs = stats[pm][1];
                float nv[8];
                #pragma unroll
                for (int j = 0; j < 8; ++j){
                    int d = pg*8 + j;
                    nv[j] = (zq[pm*512 + d] - mean)*rs*g1[d] + be1[d];
                }
                *(float4*)&hres[pm*512 + pg*8]     = make_float4(nv[0], nv[1], nv[2], nv[3]);
                *(float4*)&hres[pm*512 + pg*8 + 4] = make_float4(nv[4], nv[5], nv[6], nv[7]);
                union { ushort s[8]; uint4 u; } pk;
                #pragma unroll
                for (int j = 0; j < 8; ++j) pk.s[j] = f2bf(nv[j]);
                hA[pg*17 + pm] = pk.u;
            }
            __syncthreads();

            // ======== P4: FF1 + relu -> ffb (global bf16, block-local) ====
            {
                const uint4* Bg = (const uint4*)(wsw + 2097152 + (size_t)l*1048576);
                const float* fb = ff_b1 + l*2048;
                floatx4 acc[8] = {};
                for (int kb = 0; kb < 16; ++kb){
                    short8 af = as_short8(hA[(kb*4 + qd)*17 + li]);
                    #pragma unroll
                    for (int c = 0; c < 8; ++c){
                        int n = (w*8 + c)*16 + li;
                        short8 bf = as_short8(Bg[(size_t)(kb*4 + qd)*2048 + n]);
                        acc[c] = __builtin_amdgcn_mfma_f32_16x16x32_bf16(af, bf, acc[c], 0, 0, 0);
                    }
                }
                #pragma unroll
                for (int c = 0; c < 8; ++c){
                    #pragma unroll
                    for (int r = 0; r < 4; ++r){
                        int m = qd*4 + r;
                        int n = (w*8 + c)*16 + li;
                        float v = acc[c][r] + fb[n];
                        ffb[m*2048 + n] = f2bf(fmaxf(v, 0.0f));
                    }
                }
            }
            __syncthreads();

            // ======== P5: FF2 (K=2048 in 4 chunks through hA) ========
            {
                const uint4* Bg = (const uint4*)(wsw + 4194304 + (size_t)l*1048576);
                floatx4 acc[2] = {};
                for (int chunk = 0; chunk < 4; ++chunk){
                    if (chunk) __syncthreads();
                    // pack chunk of ffb into hA
                    hA[pg*17 + pm] = *(const uint4*)&ffb[pm*2048 + chunk*512 + pg*8];
                    __syncthreads();
                    for (int kb = 0; kb < 16; ++kb){
                        short8 af = as_short8(hA[(kb*4 + qd)*17 + li]);
                        #pragma unroll
                        for (int c = 0; c < 2; ++c){
                            int n = (w*2 + c)*16 + li;
                            short8 bf = as_short8(Bg[(size_t)((chunk*16 + kb)*4 + qd)*512 + n]);
                            acc[c] = __builtin_amdgcn_mfma_f32_16x16x32_bf16(af, bf, acc[c], 0, 0, 0);
                        }
                    }
                }
                const float* fb = ff_b2 + l*512;
                float ps[4] = {}, pq2[4] = {};
                #pragma unroll
                for (int c = 0; c < 2; ++c){
                    #pragma unroll
                    for (int r = 0; r < 4; ++r){
                        int m = qd*4 + r;
                        int n = (w*2 + c)*16 + li;
                        float zv = acc[c][r] + fb[n] + hres[m*512 + n];
                        zq[m*512 + n] = zv;
                        ps[r] += zv; pq2[r] += zv*zv;
                    }
                }
                #pragma unroll
                for (int off = 1; off < 16; off <<= 1){
                    #pragma unroll
                    for (int r = 0; r < 4; ++r){
                        ps[r]  += __shfl_xor(ps[r],  off);
                        pq2[r] += __shfl_xor(pq2[r], off);
                    }
                }
                if (li == 0){
                    #pragma unroll
                    for (int r = 0; r < 4; ++r){
                        pstat[w][qd*4 + r][0] = ps[r];
                        pstat[w][qd*4 + r][1] = pq2[r];
                    }
                }
            }
            __syncthreads();
            if (tid < 16){
                float s = 0.f, sq = 0.f;
                #pragma unroll
                for (int wv = 0; wv < 16; ++wv){ s += pstat[wv][tid][0]; sq += pstat[wv][tid][1]; }
                float mean = s * (1.0f/512.0f);
                float var  = sq * (1.0f/512.0f) - mean*mean;
                stats[tid][0] = mean;
                stats[tid][1] = rsqrtf(var + 1e-5f);
            }
            __syncthreads();

            // ======== P5b: LN2 (+ head + next-t embed when l==1) ========
            {
                const float* g2  = ln2_s + l*512;
                const float* be2 = ln2_b + l*512;
                float mean = stats[pm][0], rs = stats[pm][1];
                float nv[8];
                #pragma unroll
                for (int j = 0; j < 8; ++j){
                    int d = pg*8 + j;
                    nv[j] = (zq[pm*512 + d] - mean)*rs*g2[d] + be2[d];
                }
                if (l == 0){
                    *(float4*)&hres[pm*512 + pg*8]     = make_float4(nv[0], nv[1], nv[2], nv[3]);
                    *(float4*)&hres[pm*512 + pg*8 + 4] = make_float4(nv[4], nv[5], nv[6], nv[7]);
                } else {
                    // head partial dots: this thread covers cols pg*8..pg*8+7 of row pm
                    float s0 = 0.f, s1 = 0.f, s2 = 0.f;
                    #pragma unroll
                    for (int j = 0; j < 8; ++j){
                        int d = pg*8 + j;
                        s0 += nv[j]*hw[d*3 + 0];
                        s1 += nv[j]*hw[d*3 + 1];
                        s2 += nv[j]*hw[d*3 + 2];
                    }
                    // within wave: lanes with same pm are lane, lane^16, lane^32, lane^48
                    s0 += __shfl_xor(s0, 16); s0 += __shfl_xor(s0, 32);
                    s1 += __shfl_xor(s1, 16); s1 += __shfl_xor(s1, 32);
                    s2 += __shfl_xor(s2, 16); s2 += __shfl_xor(s2, 32);
                    if (lane < 16){
                        yacc[w][lane][0] = s0; yacc[w][lane][1] = s1; yacc[w][lane][2] = s2;
                    }
                    __syncthreads();
                    if (tid < 48){
                        int m = tid / 3, k = tid % 3;
                        float y = hb[k];
                        #pragma unroll
                        for (int wv = 0; wv < 16; ++wv) y += yacc[wv][m][k];
                        out[((size_t)(blk*16 + m)*16 + t)*3 + k] = y;
                        ybc[m][k] = y;
                    }
                    __syncthreads();
                    if (t < 15){
                        int b = blk*16 + pm;
                        float y0 = ybc[pm][0], y1 = ybc[pm][1], y2 = ybc[pm][2];
                        #pragma unroll
                        for (int j = 0; j < 8; ++j){
                            int d = pg*8 + j;
                            int e = d & ~1;
                            float div = expf(-(float)e * (9.210340371976184f / 512.0f));
                            float arg = (float)(t + 1) * div;
                            float pe = (d & 1) ? cosf(arg) : sinf(arg);
                            float acc = ip_b[d] + pe;
                            #pragma unroll
                            for (int i = 0; i < 4; ++i)
                                acc += x[((size_t)b*16 + t + 1)*7 + i] * ip_w[i*512 + d];
                            acc += y0*ip_w[4*512 + d] + y1*ip_w[5*512 + d] + y2*ip_w[6*512 + d];
                            hres[pm*512 + d] = acc;
                        }
                    }
                }
            }
            __syncthreads();
        }
    }
}

// ---------------------------------------------------------------------------
extern "C" void kernel_launch(void* const* d_in, const int* in_sizes, int n_in,
                              void* d_out, int out_size, void* d_ws, size_t ws_size,
                              hipStream_t stream)
{
    const float* x     = (const float*)d_in[0];
    const float* ip_w  = (const float*)d_in[1];
    const float* ip_b  = (const float*)d_in[2];
    const float* qkv_w = (const float*)d_in[3];
    const float* qkv_b = (const float*)d_in[4];
    const float* out_w = (const float*)d_in[5];
    const float* out_b = (const float*)d_in[6];
    const float* ln1_s = (const float*)d_in[7];
    const float* ln1_b = (const float*)d_in[8];
    const float* ff_w1 = (const float*)d_in[9];
    const float* ff_b1 = (const float*)d_in[10];
    const float* ff_w2 = (const float*)d_in[11];
    const float* ff_b2 = (const float*)d_in[12];
    const float* ln2_s = (const float*)d_in[13];
    const float* ln2_b = (const float*)d_in[14];
    const float* hw    = (const float*)d_in[15];
    const float* hb    = (const float*)d_in[16];
    float* out = (float*)d_out;

    // ws layout (bytes): wsw 12,582,912 | hres_g 1M | ffb_g 2M | kc 16M | vc 16M
    ushort* wsw   = (ushort*)d_ws;
    float* hres_g = (float*)((char*)d_ws + 12582912);
    ushort* ffb_g = (ushort*)(hres_g + 262144);
    ushort* kc    = ffb_g + 1048576;
    ushort* vc    = kc + 8388608;

    swz_k<<<dim3(32, 64, 8), 256, 0, stream>>>(qkv_w, out_w, ff_w1, ff_w2, wsw);

    rowchain_k<<<32, 1024, 0, stream>>>(
        x, wsw, ip_w, ip_b, qkv_b, out_b, ln1_s, ln1_b,
        ff_b1, ff_b2, ln2_s, ln2_b, hw, hb, out,
        hres_g, ffb_g, kc, vc);
}